// Round 12
// baseline (666.212 us; speedup 1.0000x reference)
//
#include <hip/hip_runtime.h>
#include <hip/hip_bf16.h>
#include <math.h>

#define HID 128
#define SLOPE 0.01f
#define LN_EPS 1e-5f
#define NB_SCAN 256
#define NT_SCAN 256
#define BSHIFT 6     // 64 dst nodes per bucket
#define SUBLOG 5     // 32 sub-segments per bucket

__device__ __forceinline__ float bf16lo(unsigned int v) {
  unsigned int b = v << 16;
  return __builtin_bit_cast(float, b);
}
__device__ __forceinline__ float bf16hi(unsigned int v) {
  unsigned int b = v & 0xFFFF0000u;
  return __builtin_bit_cast(float, b);
}
__device__ __forceinline__ unsigned int pack_bf16(float lo, float hi) {
  __hip_bfloat16 a = __float2bfloat16(lo);
  __hip_bfloat16 b = __float2bfloat16(hi);
  return (unsigned int)__builtin_bit_cast(unsigned short, a) |
         ((unsigned int)__builtin_bit_cast(unsigned short, b) << 16);
}
// sub-segment id: low 3 bits == (blockIdx%8) in the 256-thread scatter grid,
// so each segment is written by a single XCD (deterministic fn of edge index).
__device__ __forceinline__ int subidx(int e) {
  return ((e >> 8) & 7) | (((e >> 11) & 3) << 3);
}

__global__ void zero_int_kernel(int* __restrict__ p, int n) {
  int i = blockIdx.x * blockDim.x + threadIdx.x;
  if (i < n) p[i] = 0;
}

__global__ void hist2_kernel(const int* __restrict__ dst, int* __restrict__ cnt2, int E) {
  int e = blockIdx.x * blockDim.x + threadIdx.x;
  if (e >= E) return;
  int key = ((dst[e] >> BSHIFT) << SUBLOG) | subidx(e);
  atomicAdd(&cnt2[key], 1);
}

// 3-pass exclusive scan over m elements -> rowptr[0..m], rowptr[m]=total
__global__ void scan_pass1(const int* __restrict__ cnt, int* __restrict__ blocksum, int m) {
  __shared__ int ss[NT_SCAN];
  int K = (m + NB_SCAN * NT_SCAN - 1) / (NB_SCAN * NT_SCAN);
  int t = threadIdx.x, b = blockIdx.x;
  int beg = (b * NT_SCAN + t) * K;
  int end = min(beg + K, m);
  int s = 0;
  for (int i = beg; i < end; ++i) s += cnt[i];
  ss[t] = s;
  __syncthreads();
  for (int off = NT_SCAN / 2; off > 0; off >>= 1) {
    if (t < off) ss[t] += ss[t + off];
    __syncthreads();
  }
  if (t == 0) blocksum[b] = ss[0];
}

__global__ void scan_pass2(int* __restrict__ blocksum) {
  __shared__ int ss[NB_SCAN];
  int t = threadIdx.x;
  ss[t] = blocksum[t];
  __syncthreads();
  for (int off = 1; off < NB_SCAN; off <<= 1) {
    int v = (t >= off) ? ss[t - off] : 0;
    __syncthreads();
    ss[t] += v;
    __syncthreads();
  }
  blocksum[t] = (t == 0) ? 0 : ss[t - 1];
}

// pass3: write rowptr (exclusive) AND bucket cursors (same values)
__global__ void scan_pass3(const int* __restrict__ cnt, const int* __restrict__ blockoff,
                           int* __restrict__ rowptr, int* __restrict__ bcur, int m) {
  __shared__ int ss[NT_SCAN];
  int K = (m + NB_SCAN * NT_SCAN - 1) / (NB_SCAN * NT_SCAN);
  int t = threadIdx.x, b = blockIdx.x;
  int beg = (b * NT_SCAN + t) * K;
  int end = min(beg + K, m);
  int s = 0;
  for (int i = beg; i < end; ++i) s += cnt[i];
  ss[t] = s;
  __syncthreads();
  for (int off = 1; off < NT_SCAN; off <<= 1) {
    int v = (t >= off) ? ss[t - off] : 0;
    __syncthreads();
    ss[t] += v;
    __syncthreads();
  }
  int pre = blockoff[b] + ((t == 0) ? 0 : ss[t - 1]);
  for (int i = beg; i < end; ++i) {
    rowptr[i] = pre;
    bcur[i] = pre;
    pre += cnt[i];
    if (i == m - 1) rowptr[m] = pre;
  }
}

// scatter (src,dst) into dst-bucketed, XCD-aligned sub-segments
__global__ void bucket_scatter_kernel(const int* __restrict__ src, const int* __restrict__ dst,
                                      int* __restrict__ bcur, uint2* __restrict__ ebuf, int E) {
  int e = blockIdx.x * blockDim.x + threadIdx.x;
  if (e >= E) return;
  int s = src[e], d = dst[e];
  int key = ((d >> BSHIFT) << SUBLOG) | subidx(e);
  int pos = atomicAdd(&bcur[key], 1);
  ebuf[pos] = make_uint2((unsigned)s, (unsigned)d);
}

// per-bucket: degree count in LDS -> per-node rowptr (bucket base + wave scan),
// countdown cnt, dinv.  One block per bucket.
__global__ __launch_bounds__(256) void deg_rowptr_kernel(
    const uint2* __restrict__ ebuf, const int* __restrict__ rowptr2,
    int* __restrict__ rowptr, int* __restrict__ cnt, float* __restrict__ dinv,
    int n, int nbuck, int E) {
  __shared__ int sdeg[64];
  int b = blockIdx.x, tid = threadIdx.x;
  if (tid < 64) sdeg[tid] = 0;
  __syncthreads();
  int beg = rowptr2[b << SUBLOG], end = rowptr2[(b + 1) << SUBLOG];
  for (int j = beg + tid; j < end; j += 256) atomicAdd(&sdeg[ebuf[j].y & 63], 1);
  __syncthreads();
  if (tid < 64) {
    int deg = sdeg[tid];
    int s = deg;
#pragma unroll
    for (int off = 1; off < 64; off <<= 1) {
      int v = __shfl_up(s, off);
      if (tid >= off) s += v;
    }
    int excl = s - deg;
    int nd = (b << BSHIFT) + tid;
    if (nd < n) {
      rowptr[nd] = beg + excl;
      cnt[nd] = deg;
      dinv[nd] = rsqrtf((float)(deg + 1));
    }
    if (b == nbuck - 1 && tid == 0) rowptr[n] = E;
  }
}

// countdown-fill from bucket-grouped ebuf: colsrc writes land in ~7KB L2 windows
__global__ void fill_csr2_kernel(const uint2* __restrict__ ebuf, const int* __restrict__ rowptr,
                                 int* __restrict__ cnt, int* __restrict__ colsrc, int E) {
  int e = blockIdx.x * blockDim.x + threadIdx.x;
  if (e >= E) return;
  uint2 p = ebuf[e];
  int d = (int)p.y;
  int old = atomicSub(&cnt[d], 1);
  colsrc[rowptr[d] + old - 1] = (int)p.x;
}

// Multi-row dense: out[r][j] = bias[j] + sum_k feat[r][k]*W[k][j].
// feat is f32.  BF16OUT: write packed bf16; else f32.
template<int DIM, int ROWS, bool BF16OUT>
__global__ __launch_bounds__(256) void dense_mr_kernel(
    const float* __restrict__ feat, const float* __restrict__ W,
    const float* __restrict__ bias,
    float* __restrict__ outf, unsigned int* __restrict__ outb, int nrows) {
  __shared__ unsigned int sWp[(DIM / 2) * HID];
  __shared__ float sf[ROWS * DIM];
  int tid = threadIdx.x;
  int base = blockIdx.x * ROWS;

  const int UNITS = (DIM / 2) * (HID / 4);
  for (int u = tid; u < UNITS; u += 256) {
    int k2 = u >> 5;
    int j4 = (u & 31) << 2;
    float4 a = *reinterpret_cast<const float4*>(&W[(size_t)(2 * k2) * HID + j4]);
    float4 b = *reinterpret_cast<const float4*>(&W[(size_t)(2 * k2 + 1) * HID + j4]);
    sWp[k2 * HID + j4 + 0] = pack_bf16(a.x, b.x);
    sWp[k2 * HID + j4 + 1] = pack_bf16(a.y, b.y);
    sWp[k2 * HID + j4 + 2] = pack_bf16(a.z, b.z);
    sWp[k2 * HID + j4 + 3] = pack_bf16(a.w, b.w);
  }
  int nr = min(ROWS, nrows - base);
  int tot = nr * DIM;
  const float* fp = feat + (size_t)base * DIM;
  for (int i = tid * 4; i < tot; i += 1024) {
    *reinterpret_cast<float4*>(&sf[i]) = *reinterpret_cast<const float4*>(&fp[i]);
  }
  __syncthreads();

  int j = tid & 127;
  int rr = tid >> 7;
  float bj = bias ? bias[j] : 0.0f;
  for (int r = rr; r < nr; r += 2) {
    float acc = bj;
#pragma unroll
    for (int k2 = 0; k2 < DIM / 2; ++k2) {
      unsigned int w2 = sWp[k2 * HID + j];
      acc = fmaf(sf[r * DIM + 2 * k2], bf16lo(w2), acc);
      acc = fmaf(sf[r * DIM + 2 * k2 + 1], bf16hi(w2), acc);
    }
    if (BF16OUT) {
      float other = __shfl_xor(acc, 1);
      if ((j & 1) == 0) {
        outb[((size_t)(base + r) * HID + j) >> 1] = pack_bf16(acc, other);
      }
    } else {
      outf[(size_t)(base + r) * HID + j] = acc;
    }
  }
}

// One wave per dst node; 4 lane-groups of 16, each group takes one edge per
// iteration and loads uint4 (8 bf16 channels) per lane.  Cross-group combine
// once at the end, then self-loop + bias + LN + LeakyReLU (+ head projection).
// (R9-exact edge loop: direct colsrc/dinv loads per group.)
template<bool PROJ>
__global__ void gather_norm_kernel(const int* __restrict__ rowptr,
                                   const int* __restrict__ colsrc,
                                   const uint4* __restrict__ xwb4,  // n x 16 uint4
                                   const float* __restrict__ dinv,
                                   const float* __restrict__ cb,
                                   const float* __restrict__ g,
                                   const float* __restrict__ b,
                                   const float* __restrict__ eW,
                                   const float* __restrict__ rW,
                                   float* __restrict__ outx,
                                   float4* __restrict__ table, int n_nodes) {
  int d = blockIdx.x * 4 + (threadIdx.x >> 6);
  if (d >= n_nodes) return;
  int lane = threadIdx.x & 63;
  int grp = lane >> 4;    // 0..3: which edge in the 4-edge iteration
  int t = lane & 15;      // sublane: channels 8t..8t+7

  float acc[8];
#pragma unroll
  for (int k = 0; k < 8; ++k) acc[k] = 0.0f;

  float wd = dinv[d];
  int beg = rowptr[d], end = rowptr[d + 1];
  for (int j = beg + grp; j < end; j += 4) {
    int s = colsrc[j];
    float w = dinv[s] * wd;
    uint4 v = xwb4[(size_t)s * 16 + t];
    acc[0] = fmaf(bf16lo(v.x), w, acc[0]);
    acc[1] = fmaf(bf16hi(v.x), w, acc[1]);
    acc[2] = fmaf(bf16lo(v.y), w, acc[2]);
    acc[3] = fmaf(bf16hi(v.y), w, acc[3]);
    acc[4] = fmaf(bf16lo(v.z), w, acc[4]);
    acc[5] = fmaf(bf16hi(v.z), w, acc[5]);
    acc[6] = fmaf(bf16lo(v.w), w, acc[6]);
    acc[7] = fmaf(bf16hi(v.w), w, acc[7]);
  }
  // combine the 4 groups (after this, lanes with equal t are identical)
#pragma unroll
  for (int k = 0; k < 8; ++k) {
    acc[k] += __shfl_xor(acc[k], 16);
    acc[k] += __shfl_xor(acc[k], 32);
  }
  // self loop + conv bias
  {
    float wself = wd * wd;
    uint4 v = xwb4[(size_t)d * 16 + t];
    acc[0] = fmaf(bf16lo(v.x), wself, acc[0]);
    acc[1] = fmaf(bf16hi(v.x), wself, acc[1]);
    acc[2] = fmaf(bf16lo(v.y), wself, acc[2]);
    acc[3] = fmaf(bf16hi(v.y), wself, acc[3]);
    acc[4] = fmaf(bf16lo(v.z), wself, acc[4]);
    acc[5] = fmaf(bf16hi(v.z), wself, acc[5]);
    acc[6] = fmaf(bf16lo(v.w), wself, acc[6]);
    acc[7] = fmaf(bf16hi(v.w), wself, acc[7]);
    float4 c0 = *reinterpret_cast<const float4*>(cb + 8 * t);
    float4 c1 = *reinterpret_cast<const float4*>(cb + 8 * t + 4);
    acc[0] += c0.x; acc[1] += c0.y; acc[2] += c0.z; acc[3] += c0.w;
    acc[4] += c1.x; acc[5] += c1.y; acc[6] += c1.z; acc[7] += c1.w;
  }
  // LayerNorm over 128 channels (16 sublanes x 8)
  float s = acc[0] + acc[1] + acc[2] + acc[3] + acc[4] + acc[5] + acc[6] + acc[7];
#pragma unroll
  for (int m = 1; m < 16; m <<= 1) s += __shfl_xor(s, m);
  float mu = s * (1.0f / HID);
  float sq = 0.0f;
#pragma unroll
  for (int k = 0; k < 8; ++k) {
    acc[k] -= mu;
    sq = fmaf(acc[k], acc[k], sq);
  }
#pragma unroll
  for (int m = 1; m < 16; m <<= 1) sq += __shfl_xor(sq, m);
  float rs = rsqrtf(sq * (1.0f / HID) + LN_EPS);
  float4 g0 = *reinterpret_cast<const float4*>(g + 8 * t);
  float4 g1 = *reinterpret_cast<const float4*>(g + 8 * t + 4);
  float4 b0 = *reinterpret_cast<const float4*>(b + 8 * t);
  float4 b1 = *reinterpret_cast<const float4*>(b + 8 * t + 4);
  float o[8];
  o[0] = acc[0] * rs * g0.x + b0.x;
  o[1] = acc[1] * rs * g0.y + b0.y;
  o[2] = acc[2] * rs * g0.z + b0.z;
  o[3] = acc[3] * rs * g0.w + b0.w;
  o[4] = acc[4] * rs * g1.x + b1.x;
  o[5] = acc[5] * rs * g1.y + b1.y;
  o[6] = acc[6] * rs * g1.z + b1.z;
  o[7] = acc[7] * rs * g1.w + b1.w;
#pragma unroll
  for (int k = 0; k < 8; ++k) o[k] = o[k] >= 0.0f ? o[k] : SLOPE * o[k];

  if (!PROJ) {
    if (grp == 0) {
      float4* op = reinterpret_cast<float4*>(outx + (size_t)d * HID + 8 * t);
      op[0] = make_float4(o[0], o[1], o[2], o[3]);
      op[1] = make_float4(o[4], o[5], o[6], o[7]);
    }
  } else {
    float4 eu0 = *reinterpret_cast<const float4*>(eW + 8 * t);
    float4 eu1 = *reinterpret_cast<const float4*>(eW + 8 * t + 4);
    float4 ef0 = *reinterpret_cast<const float4*>(eW + HID + 8 * t);
    float4 ef1 = *reinterpret_cast<const float4*>(eW + HID + 8 * t + 4);
    float4 ru0 = *reinterpret_cast<const float4*>(rW + 8 * t);
    float4 ru1 = *reinterpret_cast<const float4*>(rW + 8 * t + 4);
    float4 rf0 = *reinterpret_cast<const float4*>(rW + HID + 8 * t);
    float4 rf1 = *reinterpret_cast<const float4*>(rW + HID + 8 * t + 4);
    float pa = o[0]*eu0.x + o[1]*eu0.y + o[2]*eu0.z + o[3]*eu0.w
             + o[4]*eu1.x + o[5]*eu1.y + o[6]*eu1.z + o[7]*eu1.w;
    float pb = o[0]*ef0.x + o[1]*ef0.y + o[2]*ef0.z + o[3]*ef0.w
             + o[4]*ef1.x + o[5]*ef1.y + o[6]*ef1.z + o[7]*ef1.w;
    float pc = o[0]*ru0.x + o[1]*ru0.y + o[2]*ru0.z + o[3]*ru0.w
             + o[4]*ru1.x + o[5]*ru1.y + o[6]*ru1.z + o[7]*ru1.w;
    float pd = o[0]*rf0.x + o[1]*rf0.y + o[2]*rf0.z + o[3]*rf0.w
             + o[4]*rf1.x + o[5]*rf1.y + o[6]*rf1.z + o[7]*rf1.w;
#pragma unroll
    for (int m = 1; m < 16; m <<= 1) {
      pa += __shfl_xor(pa, m);
      pb += __shfl_xor(pb, m);
      pc += __shfl_xor(pc, m);
      pd += __shfl_xor(pd, m);
    }
    if (lane == 0) table[d] = make_float4(pa, pb, pc, pd);
  }
}

// one thread per prediction pair
__global__ void pair_kernel(const int* __restrict__ eu, const int* __restrict__ ef,
                            const float4* __restrict__ table,
                            const float* __restrict__ eb, const float* __restrict__ rb,
                            float* __restrict__ out_exist, float* __restrict__ out_rating,
                            int Ep) {
  int i = blockIdx.x * blockDim.x + threadIdx.x;
  if (i >= Ep) return;
  float4 tu = table[eu[i]];
  float4 tf = table[ef[i]];
  float pe = tu.x + tf.y + eb[0];
  float pr = tu.z + tf.w + rb[0];
  out_exist[i]  = 1.0f / (1.0f + expf(-pe));
  out_rating[i] = 1.0f + 4.0f / (1.0f + expf(-pr));
}

extern "C" void kernel_launch(void* const* d_in, const int* in_sizes, int n_in,
                              void* d_out, int out_size, void* d_ws, size_t ws_size,
                              hipStream_t stream) {
  const float* u_feat = (const float*)d_in[0];
  const float* f_feat = (const float*)d_in[1];
  const int*   ei     = (const int*)d_in[2];
  const int*   eu     = (const int*)d_in[3];
  const int*   ef     = (const int*)d_in[4];
  const float* u_W  = (const float*)d_in[5];
  const float* u_b  = (const float*)d_in[6];
  const float* f_W  = (const float*)d_in[7];
  const float* f_b  = (const float*)d_in[8];
  const float* c1_W = (const float*)d_in[9];
  const float* c1_b = (const float*)d_in[10];
  const float* c2_W = (const float*)d_in[11];
  const float* c2_b = (const float*)d_in[12];
  const float* n1_g = (const float*)d_in[13];
  const float* n1_b = (const float*)d_in[14];
  const float* n2_g = (const float*)d_in[15];
  const float* n2_b = (const float*)d_in[16];
  const float* e_W  = (const float*)d_in[17];
  const float* e_b  = (const float*)d_in[18];
  const float* r_W  = (const float*)d_in[19];
  const float* r_b  = (const float*)d_in[20];

  int n_u = in_sizes[0] / 64;
  int n_f = in_sizes[1] / HID;
  int n   = n_u + n_f;
  int E   = in_sizes[2] / 2;
  int Ep  = in_sizes[3];
  int nbuck = (n + (1 << BSHIFT) - 1) >> BSHIFT;
  int nkey  = nbuck << SUBLOG;

  const int* src = ei;
  const int* dst = ei + E;

  float*        x      = (float*)d_ws;                            // n*HID f32
  unsigned int* xwb    = (unsigned int*)(x + (size_t)n * HID);    // n*HID/2 uint
  float4*       table  = (float4*)(xwb + (size_t)n * (HID / 2));  // n float4
  uint2*        ebuf   = (uint2*)(table + n);                     // E uint2
  float*        dinv   = (float*)(ebuf + E);                      // n f32
  int*          cnt    = (int*)(dinv + n);                        // n int
  int*          rowptr = cnt + n;                                 // n+1 int
  int*          cnt2   = rowptr + n + 1;                          // nkey int
  int*          rowptr2= cnt2 + nkey;                             // nkey+1 int
  int*          blocksum = rowptr2 + nkey + 1;                    // NB_SCAN int
  int*          bcur   = blocksum + NB_SCAN;                      // nkey int
  int*          colsrc = bcur + nkey;                             // E int

  // ---- bucketed edge sort (by dst>>6, XCD-aligned sub-segments) ----
  zero_int_kernel<<<(nkey + 255) / 256, 256, 0, stream>>>(cnt2, nkey);
  hist2_kernel<<<(E + 255) / 256, 256, 0, stream>>>(dst, cnt2, E);
  scan_pass1<<<NB_SCAN, NT_SCAN, 0, stream>>>(cnt2, blocksum, nkey);
  scan_pass2<<<1, NB_SCAN, 0, stream>>>(blocksum);
  scan_pass3<<<NB_SCAN, NT_SCAN, 0, stream>>>(cnt2, blocksum, rowptr2, bcur, nkey);
  bucket_scatter_kernel<<<(E + 255) / 256, 256, 0, stream>>>(src, dst, bcur, ebuf, E);

  // ---- per-node rowptr/cnt/dinv from bucketed edges, then CSR fill ----
  deg_rowptr_kernel<<<nbuck, 256, 0, stream>>>(ebuf, rowptr2, rowptr, cnt, dinv,
                                               n, nbuck, E);
  fill_csr2_kernel<<<(E + 255) / 256, 256, 0, stream>>>(ebuf, rowptr, cnt, colsrc, E);

  // ---- input embeddings (f32 x) ----
  dense_mr_kernel<64, 32, false><<<(n_u + 31) / 32, 256, 0, stream>>>(
      u_feat, u_W, u_b, x, nullptr, n_u);
  dense_mr_kernel<128, 32, false><<<(n_f + 31) / 32, 256, 0, stream>>>(
      f_feat, f_W, f_b, x + (size_t)n_u * HID, nullptr, n_f);

  // ---- layer 1 ----
  dense_mr_kernel<128, 32, true><<<(n + 31) / 32, 256, 0, stream>>>(
      x, c1_W, nullptr, nullptr, xwb, n);
  gather_norm_kernel<false><<<(n + 3) / 4, 256, 0, stream>>>(
      rowptr, colsrc, (const uint4*)xwb, dinv, c1_b, n1_g, n1_b,
      nullptr, nullptr, x, nullptr, n);

  // ---- layer 2 (fused prediction-head projection) ----
  dense_mr_kernel<128, 32, true><<<(n + 31) / 32, 256, 0, stream>>>(
      x, c2_W, nullptr, nullptr, xwb, n);
  gather_norm_kernel<true><<<(n + 3) / 4, 256, 0, stream>>>(
      rowptr, colsrc, (const uint4*)xwb, dinv, c2_b, n2_g, n2_b,
      e_W, r_W, nullptr, table, n);

  // ---- per-pair combine ----
  float* out_exist  = (float*)d_out;
  float* out_rating = out_exist + Ep;
  pair_kernel<<<(Ep + 255) / 256, 256, 0, stream>>>(eu, ef, table, e_b, r_b,
                                                    out_exist, out_rating, Ep);
}

// Round 13
// 635.564 us; speedup vs baseline: 1.0482x; 1.0482x over previous
//
#include <hip/hip_runtime.h>
#include <hip/hip_bf16.h>
#include <math.h>

#define HID 128
#define SLOPE 0.01f
#define LN_EPS 1e-5f
#define NB_SCAN 256
#define NT_SCAN 256
#define BSHIFT 6     // 64 dst nodes per bucket
#define SUBLOG 5     // 32 sub-segments per bucket

__device__ __forceinline__ float bf16lo(unsigned int v) {
  unsigned int b = v << 16;
  return __builtin_bit_cast(float, b);
}
__device__ __forceinline__ float bf16hi(unsigned int v) {
  unsigned int b = v & 0xFFFF0000u;
  return __builtin_bit_cast(float, b);
}
__device__ __forceinline__ unsigned int pack_bf16(float lo, float hi) {
  __hip_bfloat16 a = __float2bfloat16(lo);
  __hip_bfloat16 b = __float2bfloat16(hi);
  return (unsigned int)__builtin_bit_cast(unsigned short, a) |
         ((unsigned int)__builtin_bit_cast(unsigned short, b) << 16);
}
// sub-segment id: low 3 bits == (blockIdx%8) in the 256-thread scatter grid,
// so each segment is written by a single XCD (deterministic fn of edge index).
__device__ __forceinline__ int subidx(int e) {
  return ((e >> 8) & 7) | (((e >> 11) & 3) << 3);
}

__global__ void zero_int_kernel(int* __restrict__ p, int n) {
  int i = blockIdx.x * blockDim.x + threadIdx.x;
  if (i < n) p[i] = 0;
}

__global__ void hist2_kernel(const int* __restrict__ dst, int* __restrict__ cnt2, int E) {
  int e = blockIdx.x * blockDim.x + threadIdx.x;
  if (e >= E) return;
  int key = ((dst[e] >> BSHIFT) << SUBLOG) | subidx(e);
  atomicAdd(&cnt2[key], 1);
}

// 3-pass exclusive scan over m elements -> rowptr[0..m], rowptr[m]=total
__global__ void scan_pass1(const int* __restrict__ cnt, int* __restrict__ blocksum, int m) {
  __shared__ int ss[NT_SCAN];
  int K = (m + NB_SCAN * NT_SCAN - 1) / (NB_SCAN * NT_SCAN);
  int t = threadIdx.x, b = blockIdx.x;
  int beg = (b * NT_SCAN + t) * K;
  int end = min(beg + K, m);
  int s = 0;
  for (int i = beg; i < end; ++i) s += cnt[i];
  ss[t] = s;
  __syncthreads();
  for (int off = NT_SCAN / 2; off > 0; off >>= 1) {
    if (t < off) ss[t] += ss[t + off];
    __syncthreads();
  }
  if (t == 0) blocksum[b] = ss[0];
}

__global__ void scan_pass2(int* __restrict__ blocksum) {
  __shared__ int ss[NB_SCAN];
  int t = threadIdx.x;
  ss[t] = blocksum[t];
  __syncthreads();
  for (int off = 1; off < NB_SCAN; off <<= 1) {
    int v = (t >= off) ? ss[t - off] : 0;
    __syncthreads();
    ss[t] += v;
    __syncthreads();
  }
  blocksum[t] = (t == 0) ? 0 : ss[t - 1];
}

// pass3: write rowptr (exclusive) AND bucket cursors (same values)
__global__ void scan_pass3(const int* __restrict__ cnt, const int* __restrict__ blockoff,
                           int* __restrict__ rowptr, int* __restrict__ bcur, int m) {
  __shared__ int ss[NT_SCAN];
  int K = (m + NB_SCAN * NT_SCAN - 1) / (NB_SCAN * NT_SCAN);
  int t = threadIdx.x, b = blockIdx.x;
  int beg = (b * NT_SCAN + t) * K;
  int end = min(beg + K, m);
  int s = 0;
  for (int i = beg; i < end; ++i) s += cnt[i];
  ss[t] = s;
  __syncthreads();
  for (int off = 1; off < NT_SCAN; off <<= 1) {
    int v = (t >= off) ? ss[t - off] : 0;
    __syncthreads();
    ss[t] += v;
    __syncthreads();
  }
  int pre = blockoff[b] + ((t == 0) ? 0 : ss[t - 1]);
  for (int i = beg; i < end; ++i) {
    rowptr[i] = pre;
    bcur[i] = pre;
    pre += cnt[i];
    if (i == m - 1) rowptr[m] = pre;
  }
}

// scatter (src,dst) into dst-bucketed, XCD-aligned sub-segments
__global__ void bucket_scatter_kernel(const int* __restrict__ src, const int* __restrict__ dst,
                                      int* __restrict__ bcur, uint2* __restrict__ ebuf, int E) {
  int e = blockIdx.x * blockDim.x + threadIdx.x;
  if (e >= E) return;
  int s = src[e], d = dst[e];
  int key = ((d >> BSHIFT) << SUBLOG) | subidx(e);
  int pos = atomicAdd(&bcur[key], 1);
  ebuf[pos] = make_uint2((unsigned)s, (unsigned)d);
}

// per-bucket: degree count in LDS -> per-node rowptr (bucket base + wave scan),
// countdown cnt, dinv.  One block per bucket.
__global__ __launch_bounds__(256) void deg_rowptr_kernel(
    const uint2* __restrict__ ebuf, const int* __restrict__ rowptr2,
    int* __restrict__ rowptr, int* __restrict__ cnt, float* __restrict__ dinv,
    int n, int nbuck, int E) {
  __shared__ int sdeg[64];
  int b = blockIdx.x, tid = threadIdx.x;
  if (tid < 64) sdeg[tid] = 0;
  __syncthreads();
  int beg = rowptr2[b << SUBLOG], end = rowptr2[(b + 1) << SUBLOG];
  for (int j = beg + tid; j < end; j += 256) atomicAdd(&sdeg[ebuf[j].y & 63], 1);
  __syncthreads();
  if (tid < 64) {
    int deg = sdeg[tid];
    int s = deg;
#pragma unroll
    for (int off = 1; off < 64; off <<= 1) {
      int v = __shfl_up(s, off);
      if (tid >= off) s += v;
    }
    int excl = s - deg;
    int nd = (b << BSHIFT) + tid;
    if (nd < n) {
      rowptr[nd] = beg + excl;
      cnt[nd] = deg;
      dinv[nd] = rsqrtf((float)(deg + 1));
    }
    if (b == nbuck - 1 && tid == 0) rowptr[n] = E;
  }
}

// countdown-fill from bucket-grouped ebuf: ecol = (src, dinv[s]*dinv[d]) pairs,
// writes land in ~15KB L2 windows
__global__ void fill_csr2_kernel(const uint2* __restrict__ ebuf, const int* __restrict__ rowptr,
                                 const float* __restrict__ dinv,
                                 int* __restrict__ cnt, uint2* __restrict__ ecol, int E) {
  int e = blockIdx.x * blockDim.x + threadIdx.x;
  if (e >= E) return;
  uint2 p = ebuf[e];
  int d = (int)p.y;
  int old = atomicSub(&cnt[d], 1);
  float w = dinv[p.x] * dinv[d];
  ecol[rowptr[d] + old - 1] = make_uint2(p.x, __builtin_bit_cast(unsigned int, w));
}

// Multi-row dense: out[r][j] = bias[j] + sum_k feat[r][k]*W[k][j].
// W column j staged in REGISTERS (packed bf16 pairs); rows staged in LDS.
// feat is f32.  BF16OUT: write packed bf16; else f32.
template<int DIM, int ROWS, bool BF16OUT>
__global__ __launch_bounds__(256) void dense_mr_kernel(
    const float* __restrict__ feat, const float* __restrict__ W,
    const float* __restrict__ bias,
    float* __restrict__ outf, unsigned int* __restrict__ outb, int nrows) {
  __shared__ float sf[ROWS * DIM];
  int tid = threadIdx.x;
  int base = blockIdx.x * ROWS;
  int j = tid & 127;
  int rr = tid >> 7;

  // W column j -> registers (packed bf16 over k-pairs; full unroll = static idx)
  unsigned int wreg[DIM / 2];
#pragma unroll
  for (int k2 = 0; k2 < DIM / 2; ++k2) {
    wreg[k2] = pack_bf16(W[(size_t)(2 * k2) * HID + j],
                         W[(size_t)(2 * k2 + 1) * HID + j]);
  }

  int nr = min(ROWS, nrows - base);
  int tot = nr * DIM;
  const float* fp = feat + (size_t)base * DIM;
  for (int i = tid * 4; i < tot; i += 1024) {
    *reinterpret_cast<float4*>(&sf[i]) = *reinterpret_cast<const float4*>(&fp[i]);
  }
  __syncthreads();

  float bj = bias ? bias[j] : 0.0f;
  for (int r = rr; r < nr; r += 2) {
    float acc = bj;
    const float4* row4 = reinterpret_cast<const float4*>(&sf[r * DIM]);
#pragma unroll
    for (int k4 = 0; k4 < DIM / 4; ++k4) {
      float4 xv = row4[k4];
      unsigned int wa = wreg[2 * k4];
      unsigned int wb = wreg[2 * k4 + 1];
      acc = fmaf(xv.x, bf16lo(wa), acc);
      acc = fmaf(xv.y, bf16hi(wa), acc);
      acc = fmaf(xv.z, bf16lo(wb), acc);
      acc = fmaf(xv.w, bf16hi(wb), acc);
    }
    if (BF16OUT) {
      float other = __shfl_xor(acc, 1);
      if ((j & 1) == 0) {
        outb[((size_t)(base + r) * HID + j) >> 1] = pack_bf16(acc, other);
      }
    } else {
      outf[(size_t)(base + r) * HID + j] = acc;
    }
  }
}

// One wave per dst node; 4 lane-groups of 16, each group takes one edge per
// iteration: one uint2 (src, weight) broadcast load + one uint4 row load/lane.
// Cross-group combine once at the end, then self-loop + bias + LN + LeakyReLU
// (+ head projection).  (R9-form summation order preserved.)
template<bool PROJ>
__global__ void gather_norm_kernel(const int* __restrict__ rowptr,
                                   const uint2* __restrict__ ecol,  // (src, w) per edge
                                   const uint4* __restrict__ xwb4,  // n x 16 uint4
                                   const float* __restrict__ dinv,
                                   const float* __restrict__ cb,
                                   const float* __restrict__ g,
                                   const float* __restrict__ b,
                                   const float* __restrict__ eW,
                                   const float* __restrict__ rW,
                                   float* __restrict__ outx,
                                   float4* __restrict__ table, int n_nodes) {
  int d = blockIdx.x * 4 + (threadIdx.x >> 6);
  if (d >= n_nodes) return;
  int lane = threadIdx.x & 63;
  int grp = lane >> 4;    // 0..3: which edge in the 4-edge iteration
  int t = lane & 15;      // sublane: channels 8t..8t+7

  float acc[8];
#pragma unroll
  for (int k = 0; k < 8; ++k) acc[k] = 0.0f;

  float wd = dinv[d];
  int beg = rowptr[d], end = rowptr[d + 1];
  for (int j = beg + grp; j < end; j += 4) {
    uint2 e = ecol[j];
    float w = __builtin_bit_cast(float, e.y);
    uint4 v = xwb4[(size_t)e.x * 16 + t];
    acc[0] = fmaf(bf16lo(v.x), w, acc[0]);
    acc[1] = fmaf(bf16hi(v.x), w, acc[1]);
    acc[2] = fmaf(bf16lo(v.y), w, acc[2]);
    acc[3] = fmaf(bf16hi(v.y), w, acc[3]);
    acc[4] = fmaf(bf16lo(v.z), w, acc[4]);
    acc[5] = fmaf(bf16hi(v.z), w, acc[5]);
    acc[6] = fmaf(bf16lo(v.w), w, acc[6]);
    acc[7] = fmaf(bf16hi(v.w), w, acc[7]);
  }
  // combine the 4 groups (after this, lanes with equal t are identical)
#pragma unroll
  for (int k = 0; k < 8; ++k) {
    acc[k] += __shfl_xor(acc[k], 16);
    acc[k] += __shfl_xor(acc[k], 32);
  }
  // self loop + conv bias
  {
    float wself = wd * wd;
    uint4 v = xwb4[(size_t)d * 16 + t];
    acc[0] = fmaf(bf16lo(v.x), wself, acc[0]);
    acc[1] = fmaf(bf16hi(v.x), wself, acc[1]);
    acc[2] = fmaf(bf16lo(v.y), wself, acc[2]);
    acc[3] = fmaf(bf16hi(v.y), wself, acc[3]);
    acc[4] = fmaf(bf16lo(v.z), wself, acc[4]);
    acc[5] = fmaf(bf16hi(v.z), wself, acc[5]);
    acc[6] = fmaf(bf16lo(v.w), wself, acc[6]);
    acc[7] = fmaf(bf16hi(v.w), wself, acc[7]);
    float4 c0 = *reinterpret_cast<const float4*>(cb + 8 * t);
    float4 c1 = *reinterpret_cast<const float4*>(cb + 8 * t + 4);
    acc[0] += c0.x; acc[1] += c0.y; acc[2] += c0.z; acc[3] += c0.w;
    acc[4] += c1.x; acc[5] += c1.y; acc[6] += c1.z; acc[7] += c1.w;
  }
  // LayerNorm over 128 channels (16 sublanes x 8)
  float s = acc[0] + acc[1] + acc[2] + acc[3] + acc[4] + acc[5] + acc[6] + acc[7];
#pragma unroll
  for (int m = 1; m < 16; m <<= 1) s += __shfl_xor(s, m);
  float mu = s * (1.0f / HID);
  float sq = 0.0f;
#pragma unroll
  for (int k = 0; k < 8; ++k) {
    acc[k] -= mu;
    sq = fmaf(acc[k], acc[k], sq);
  }
#pragma unroll
  for (int m = 1; m < 16; m <<= 1) sq += __shfl_xor(sq, m);
  float rs = rsqrtf(sq * (1.0f / HID) + LN_EPS);
  float4 g0 = *reinterpret_cast<const float4*>(g + 8 * t);
  float4 g1 = *reinterpret_cast<const float4*>(g + 8 * t + 4);
  float4 b0 = *reinterpret_cast<const float4*>(b + 8 * t);
  float4 b1 = *reinterpret_cast<const float4*>(b + 8 * t + 4);
  float o[8];
  o[0] = acc[0] * rs * g0.x + b0.x;
  o[1] = acc[1] * rs * g0.y + b0.y;
  o[2] = acc[2] * rs * g0.z + b0.z;
  o[3] = acc[3] * rs * g0.w + b0.w;
  o[4] = acc[4] * rs * g1.x + b1.x;
  o[5] = acc[5] * rs * g1.y + b1.y;
  o[6] = acc[6] * rs * g1.z + b1.z;
  o[7] = acc[7] * rs * g1.w + b1.w;
#pragma unroll
  for (int k = 0; k < 8; ++k) o[k] = o[k] >= 0.0f ? o[k] : SLOPE * o[k];

  if (!PROJ) {
    if (grp == 0) {
      float4* op = reinterpret_cast<float4*>(outx + (size_t)d * HID + 8 * t);
      op[0] = make_float4(o[0], o[1], o[2], o[3]);
      op[1] = make_float4(o[4], o[5], o[6], o[7]);
    }
  } else {
    float4 eu0 = *reinterpret_cast<const float4*>(eW + 8 * t);
    float4 eu1 = *reinterpret_cast<const float4*>(eW + 8 * t + 4);
    float4 ef0 = *reinterpret_cast<const float4*>(eW + HID + 8 * t);
    float4 ef1 = *reinterpret_cast<const float4*>(eW + HID + 8 * t + 4);
    float4 ru0 = *reinterpret_cast<const float4*>(rW + 8 * t);
    float4 ru1 = *reinterpret_cast<const float4*>(rW + 8 * t + 4);
    float4 rf0 = *reinterpret_cast<const float4*>(rW + HID + 8 * t);
    float4 rf1 = *reinterpret_cast<const float4*>(rW + HID + 8 * t + 4);
    float pa = o[0]*eu0.x + o[1]*eu0.y + o[2]*eu0.z + o[3]*eu0.w
             + o[4]*eu1.x + o[5]*eu1.y + o[6]*eu1.z + o[7]*eu1.w;
    float pb = o[0]*ef0.x + o[1]*ef0.y + o[2]*ef0.z + o[3]*ef0.w
             + o[4]*ef1.x + o[5]*ef1.y + o[6]*ef1.z + o[7]*ef1.w;
    float pc = o[0]*ru0.x + o[1]*ru0.y + o[2]*ru0.z + o[3]*ru0.w
             + o[4]*ru1.x + o[5]*ru1.y + o[6]*ru1.z + o[7]*ru1.w;
    float pd = o[0]*rf0.x + o[1]*rf0.y + o[2]*rf0.z + o[3]*rf0.w
             + o[4]*rf1.x + o[5]*rf1.y + o[6]*rf1.z + o[7]*rf1.w;
#pragma unroll
    for (int m = 1; m < 16; m <<= 1) {
      pa += __shfl_xor(pa, m);
      pb += __shfl_xor(pb, m);
      pc += __shfl_xor(pc, m);
      pd += __shfl_xor(pd, m);
    }
    if (lane == 0) table[d] = make_float4(pa, pb, pc, pd);
  }
}

// one thread per prediction pair
__global__ void pair_kernel(const int* __restrict__ eu, const int* __restrict__ ef,
                            const float4* __restrict__ table,
                            const float* __restrict__ eb, const float* __restrict__ rb,
                            float* __restrict__ out_exist, float* __restrict__ out_rating,
                            int Ep) {
  int i = blockIdx.x * blockDim.x + threadIdx.x;
  if (i >= Ep) return;
  float4 tu = table[eu[i]];
  float4 tf = table[ef[i]];
  float pe = tu.x + tf.y + eb[0];
  float pr = tu.z + tf.w + rb[0];
  out_exist[i]  = 1.0f / (1.0f + expf(-pe));
  out_rating[i] = 1.0f + 4.0f / (1.0f + expf(-pr));
}

extern "C" void kernel_launch(void* const* d_in, const int* in_sizes, int n_in,
                              void* d_out, int out_size, void* d_ws, size_t ws_size,
                              hipStream_t stream) {
  const float* u_feat = (const float*)d_in[0];
  const float* f_feat = (const float*)d_in[1];
  const int*   ei     = (const int*)d_in[2];
  const int*   eu     = (const int*)d_in[3];
  const int*   ef     = (const int*)d_in[4];
  const float* u_W  = (const float*)d_in[5];
  const float* u_b  = (const float*)d_in[6];
  const float* f_W  = (const float*)d_in[7];
  const float* f_b  = (const float*)d_in[8];
  const float* c1_W = (const float*)d_in[9];
  const float* c1_b = (const float*)d_in[10];
  const float* c2_W = (const float*)d_in[11];
  const float* c2_b = (const float*)d_in[12];
  const float* n1_g = (const float*)d_in[13];
  const float* n1_b = (const float*)d_in[14];
  const float* n2_g = (const float*)d_in[15];
  const float* n2_b = (const float*)d_in[16];
  const float* e_W  = (const float*)d_in[17];
  const float* e_b  = (const float*)d_in[18];
  const float* r_W  = (const float*)d_in[19];
  const float* r_b  = (const float*)d_in[20];

  int n_u = in_sizes[0] / 64;
  int n_f = in_sizes[1] / HID;
  int n   = n_u + n_f;
  int E   = in_sizes[2] / 2;
  int Ep  = in_sizes[3];
  int nbuck = (n + (1 << BSHIFT) - 1) >> BSHIFT;
  int nkey  = nbuck << SUBLOG;

  const int* src = ei;
  const int* dst = ei + E;

  float*        x      = (float*)d_ws;                            // n*HID f32
  unsigned int* xwb    = (unsigned int*)(x + (size_t)n * HID);    // n*HID/2 uint
  float4*       table  = (float4*)(xwb + (size_t)n * (HID / 2));  // n float4
  uint2*        ebuf   = (uint2*)(table + n);                     // E uint2
  uint2*        ecol   = ebuf + E;                                // E uint2 (src, w)
  float*        dinv   = (float*)(ecol + E);                      // n f32
  int*          cnt    = (int*)(dinv + n);                        // n int
  int*          rowptr = cnt + n;                                 // n+1 int
  int*          cnt2   = rowptr + n + 1;                          // nkey int
  int*          rowptr2= cnt2 + nkey;                             // nkey+1 int
  int*          blocksum = rowptr2 + nkey + 1;                    // NB_SCAN int
  int*          bcur   = blocksum + NB_SCAN;                      // nkey int

  // ---- bucketed edge sort (by dst>>6, XCD-aligned sub-segments) ----
  zero_int_kernel<<<(nkey + 255) / 256, 256, 0, stream>>>(cnt2, nkey);
  hist2_kernel<<<(E + 255) / 256, 256, 0, stream>>>(dst, cnt2, E);
  scan_pass1<<<NB_SCAN, NT_SCAN, 0, stream>>>(cnt2, blocksum, nkey);
  scan_pass2<<<1, NB_SCAN, 0, stream>>>(blocksum);
  scan_pass3<<<NB_SCAN, NT_SCAN, 0, stream>>>(cnt2, blocksum, rowptr2, bcur, nkey);
  bucket_scatter_kernel<<<(E + 255) / 256, 256, 0, stream>>>(src, dst, bcur, ebuf, E);

  // ---- per-node rowptr/cnt/dinv from bucketed edges, then CSR fill ----
  deg_rowptr_kernel<<<nbuck, 256, 0, stream>>>(ebuf, rowptr2, rowptr, cnt, dinv,
                                               n, nbuck, E);
  fill_csr2_kernel<<<(E + 255) / 256, 256, 0, stream>>>(ebuf, rowptr, dinv, cnt, ecol, E);

  // ---- input embeddings (f32 x) ----
  dense_mr_kernel<64, 32, false><<<(n_u + 31) / 32, 256, 0, stream>>>(
      u_feat, u_W, u_b, x, nullptr, n_u);
  dense_mr_kernel<128, 32, false><<<(n_f + 31) / 32, 256, 0, stream>>>(
      f_feat, f_W, f_b, x + (size_t)n_u * HID, nullptr, n_f);

  // ---- layer 1 ----
  dense_mr_kernel<128, 32, true><<<(n + 31) / 32, 256, 0, stream>>>(
      x, c1_W, nullptr, nullptr, xwb, n);
  gather_norm_kernel<false><<<(n + 3) / 4, 256, 0, stream>>>(
      rowptr, ecol, (const uint4*)xwb, dinv, c1_b, n1_g, n1_b,
      nullptr, nullptr, x, nullptr, n);

  // ---- layer 2 (fused prediction-head projection) ----
  dense_mr_kernel<128, 32, true><<<(n + 31) / 32, 256, 0, stream>>>(
      x, c2_W, nullptr, nullptr, xwb, n);
  gather_norm_kernel<true><<<(n + 3) / 4, 256, 0, stream>>>(
      rowptr, ecol, (const uint4*)xwb, dinv, c2_b, n2_g, n2_b,
      e_W, r_W, nullptr, table, n);

  // ---- per-pair combine ----
  float* out_exist  = (float*)d_out;
  float* out_rating = out_exist + Ep;
  pair_kernel<<<(Ep + 255) / 256, 256, 0, stream>>>(eu, ef, table, e_b, r_b,
                                                    out_exist, out_rating, Ep);
}

// Round 14
// 591.848 us; speedup vs baseline: 1.1256x; 1.0739x over previous
//
#include <hip/hip_runtime.h>
#include <hip/hip_bf16.h>
#include <math.h>

#define HID 128
#define SLOPE 0.01f
#define LN_EPS 1e-5f
#define NB_SCAN 256
#define NT_SCAN 256
#define BSHIFT 6     // 64 dst nodes per bucket
#define SUBLOG 5     // 32 sub-segments per bucket

__device__ __forceinline__ float bf16lo(unsigned int v) {
  unsigned int b = v << 16;
  return __builtin_bit_cast(float, b);
}
__device__ __forceinline__ float bf16hi(unsigned int v) {
  unsigned int b = v & 0xFFFF0000u;
  return __builtin_bit_cast(float, b);
}
__device__ __forceinline__ unsigned int pack_bf16(float lo, float hi) {
  __hip_bfloat16 a = __float2bfloat16(lo);
  __hip_bfloat16 b = __float2bfloat16(hi);
  return (unsigned int)__builtin_bit_cast(unsigned short, a) |
         ((unsigned int)__builtin_bit_cast(unsigned short, b) << 16);
}
// sub-segment id: low 3 bits == (blockIdx%8) in the 256-thread scatter grid,
// so each segment is written by a single XCD (deterministic fn of edge index).
__device__ __forceinline__ int subidx(int e) {
  return ((e >> 8) & 7) | (((e >> 11) & 3) << 3);
}

__global__ void zero_int_kernel(int* __restrict__ p, int n) {
  int i = blockIdx.x * blockDim.x + threadIdx.x;
  if (i < n) p[i] = 0;
}

__global__ void hist2_kernel(const int* __restrict__ dst, int* __restrict__ cnt2, int E) {
  int e = blockIdx.x * blockDim.x + threadIdx.x;
  if (e >= E) return;
  int key = ((dst[e] >> BSHIFT) << SUBLOG) | subidx(e);
  atomicAdd(&cnt2[key], 1);
}

// 3-pass exclusive scan over m elements -> rowptr[0..m], rowptr[m]=total
__global__ void scan_pass1(const int* __restrict__ cnt, int* __restrict__ blocksum, int m) {
  __shared__ int ss[NT_SCAN];
  int K = (m + NB_SCAN * NT_SCAN - 1) / (NB_SCAN * NT_SCAN);
  int t = threadIdx.x, b = blockIdx.x;
  int beg = (b * NT_SCAN + t) * K;
  int end = min(beg + K, m);
  int s = 0;
  for (int i = beg; i < end; ++i) s += cnt[i];
  ss[t] = s;
  __syncthreads();
  for (int off = NT_SCAN / 2; off > 0; off >>= 1) {
    if (t < off) ss[t] += ss[t + off];
    __syncthreads();
  }
  if (t == 0) blocksum[b] = ss[0];
}

__global__ void scan_pass2(int* __restrict__ blocksum) {
  __shared__ int ss[NB_SCAN];
  int t = threadIdx.x;
  ss[t] = blocksum[t];
  __syncthreads();
  for (int off = 1; off < NB_SCAN; off <<= 1) {
    int v = (t >= off) ? ss[t - off] : 0;
    __syncthreads();
    ss[t] += v;
    __syncthreads();
  }
  blocksum[t] = (t == 0) ? 0 : ss[t - 1];
}

// pass3: write rowptr (exclusive) AND bucket cursors (same values)
__global__ void scan_pass3(const int* __restrict__ cnt, const int* __restrict__ blockoff,
                           int* __restrict__ rowptr, int* __restrict__ bcur, int m) {
  __shared__ int ss[NT_SCAN];
  int K = (m + NB_SCAN * NT_SCAN - 1) / (NB_SCAN * NT_SCAN);
  int t = threadIdx.x, b = blockIdx.x;
  int beg = (b * NT_SCAN + t) * K;
  int end = min(beg + K, m);
  int s = 0;
  for (int i = beg; i < end; ++i) s += cnt[i];
  ss[t] = s;
  __syncthreads();
  for (int off = 1; off < NT_SCAN; off <<= 1) {
    int v = (t >= off) ? ss[t - off] : 0;
    __syncthreads();
    ss[t] += v;
    __syncthreads();
  }
  int pre = blockoff[b] + ((t == 0) ? 0 : ss[t - 1]);
  for (int i = beg; i < end; ++i) {
    rowptr[i] = pre;
    bcur[i] = pre;
    pre += cnt[i];
    if (i == m - 1) rowptr[m] = pre;
  }
}

// scatter packed (src<<6 | dst&63) into dst-bucketed, XCD-aligned sub-segments
__global__ void bucket_scatter_kernel(const int* __restrict__ src, const int* __restrict__ dst,
                                      int* __restrict__ bcur, unsigned int* __restrict__ ebuf,
                                      int E) {
  int e = blockIdx.x * blockDim.x + threadIdx.x;
  if (e >= E) return;
  int s = src[e], d = dst[e];
  int key = ((d >> BSHIFT) << SUBLOG) | subidx(e);
  int pos = atomicAdd(&bcur[key], 1);
  ebuf[pos] = ((unsigned)s << 6) | ((unsigned)d & 63);
}

// per-bucket: degree count in LDS -> per-node rowptr (bucket base + wave scan),
// dinv.  One block per bucket.
__global__ __launch_bounds__(256) void deg_rowptr_kernel(
    const unsigned int* __restrict__ ebuf, const int* __restrict__ rowptr2,
    int* __restrict__ rowptr, float* __restrict__ dinv,
    int n, int nbuck, int E) {
  __shared__ int sdeg[64];
  int b = blockIdx.x, tid = threadIdx.x;
  if (tid < 64) sdeg[tid] = 0;
  __syncthreads();
  int beg = rowptr2[b << SUBLOG], end = rowptr2[(b + 1) << SUBLOG];
  for (int j = beg + tid; j < end; j += 256) atomicAdd(&sdeg[ebuf[j] & 63], 1);
  __syncthreads();
  if (tid < 64) {
    int deg = sdeg[tid];
    int s = deg;
#pragma unroll
    for (int off = 1; off < 64; off <<= 1) {
      int v = __shfl_up(s, off);
      if (tid >= off) s += v;
    }
    int excl = s - deg;
    int nd = (b << BSHIFT) + tid;
    if (nd < n) {
      rowptr[nd] = beg + excl;
      dinv[nd] = rsqrtf((float)(deg + 1));
    }
    if (b == nbuck - 1 && tid == 0) rowptr[n] = E;
  }
}

// per-bucket CSR fill: LDS cursors, single-block-local ecol writes (~15KB window)
__global__ __launch_bounds__(256) void fill_bucket_kernel(
    const unsigned int* __restrict__ ebuf, const int* __restrict__ rowptr2,
    const int* __restrict__ rowptr, const float* __restrict__ dinv,
    uint2* __restrict__ ecol, int n) {
  __shared__ int scur[64];
  __shared__ int srow[64];
  __shared__ float sdinv[64];
  int b = blockIdx.x, tid = threadIdx.x;
  if (tid < 64) {
    scur[tid] = 0;
    int nd = (b << BSHIFT) + tid;
    srow[tid] = (nd < n) ? rowptr[nd] : 0;
    sdinv[tid] = (nd < n) ? dinv[nd] : 0.0f;
  }
  __syncthreads();
  int beg = rowptr2[b << SUBLOG], end = rowptr2[(b + 1) << SUBLOG];
  for (int j = beg + tid; j < end; j += 256) {
    unsigned int v = ebuf[j];
    int ndl = (int)(v & 63);
    int s = (int)(v >> 6);
    int pos = atomicAdd(&scur[ndl], 1);
    float w = dinv[s] * sdinv[ndl];
    ecol[srow[ndl] + pos] = make_uint2((unsigned)s, __builtin_bit_cast(unsigned int, w));
  }
}

// Multi-row dense: out[r][j] = bias[j] + sum_k feat[r][k]*W[k][j].
// W column j staged in REGISTERS (packed bf16 pairs); rows staged in LDS.
// feat is f32.  BF16OUT: write packed bf16; else f32.
template<int DIM, int ROWS, bool BF16OUT>
__global__ __launch_bounds__(256) void dense_mr_kernel(
    const float* __restrict__ feat, const float* __restrict__ W,
    const float* __restrict__ bias,
    float* __restrict__ outf, unsigned int* __restrict__ outb, int nrows) {
  __shared__ float sf[ROWS * DIM];
  int tid = threadIdx.x;
  int base = blockIdx.x * ROWS;
  int j = tid & 127;
  int rr = tid >> 7;

  // W column j -> registers (packed bf16 over k-pairs; full unroll = static idx)
  unsigned int wreg[DIM / 2];
#pragma unroll
  for (int k2 = 0; k2 < DIM / 2; ++k2) {
    wreg[k2] = pack_bf16(W[(size_t)(2 * k2) * HID + j],
                         W[(size_t)(2 * k2 + 1) * HID + j]);
  }

  int nr = min(ROWS, nrows - base);
  int tot = nr * DIM;
  const float* fp = feat + (size_t)base * DIM;
  for (int i = tid * 4; i < tot; i += 1024) {
    *reinterpret_cast<float4*>(&sf[i]) = *reinterpret_cast<const float4*>(&fp[i]);
  }
  __syncthreads();

  float bj = bias ? bias[j] : 0.0f;
  for (int r = rr; r < nr; r += 2) {
    float acc = bj;
    const float4* row4 = reinterpret_cast<const float4*>(&sf[r * DIM]);
#pragma unroll
    for (int k4 = 0; k4 < DIM / 4; ++k4) {
      float4 xv = row4[k4];
      unsigned int wa = wreg[2 * k4];
      unsigned int wb = wreg[2 * k4 + 1];
      acc = fmaf(xv.x, bf16lo(wa), acc);
      acc = fmaf(xv.y, bf16hi(wa), acc);
      acc = fmaf(xv.z, bf16lo(wb), acc);
      acc = fmaf(xv.w, bf16hi(wb), acc);
    }
    if (BF16OUT) {
      float other = __shfl_xor(acc, 1);
      if ((j & 1) == 0) {
        outb[((size_t)(base + r) * HID + j) >> 1] = pack_bf16(acc, other);
      }
    } else {
      outf[(size_t)(base + r) * HID + j] = acc;
    }
  }
}

// One wave per dst node; 4 lane-groups of 16, each group takes one edge per
// iteration: one uint2 (src, weight) broadcast load + one uint4 row load/lane.
// Cross-group combine once at the end, then self-loop + bias + LN + LeakyReLU
// (+ head projection).  (R9-form summation order preserved.)
template<bool PROJ>
__global__ void gather_norm_kernel(const int* __restrict__ rowptr,
                                   const uint2* __restrict__ ecol,  // (src, w) per edge
                                   const uint4* __restrict__ xwb4,  // n x 16 uint4
                                   const float* __restrict__ dinv,
                                   const float* __restrict__ cb,
                                   const float* __restrict__ g,
                                   const float* __restrict__ b,
                                   const float* __restrict__ eW,
                                   const float* __restrict__ rW,
                                   float* __restrict__ outx,
                                   float4* __restrict__ table, int n_nodes) {
  int d = blockIdx.x * 4 + (threadIdx.x >> 6);
  if (d >= n_nodes) return;
  int lane = threadIdx.x & 63;
  int grp = lane >> 4;    // 0..3: which edge in the 4-edge iteration
  int t = lane & 15;      // sublane: channels 8t..8t+7

  float acc[8];
#pragma unroll
  for (int k = 0; k < 8; ++k) acc[k] = 0.0f;

  float wd = dinv[d];
  int beg = rowptr[d], end = rowptr[d + 1];
  for (int j = beg + grp; j < end; j += 4) {
    uint2 e = ecol[j];
    float w = __builtin_bit_cast(float, e.y);
    uint4 v = xwb4[(size_t)e.x * 16 + t];
    acc[0] = fmaf(bf16lo(v.x), w, acc[0]);
    acc[1] = fmaf(bf16hi(v.x), w, acc[1]);
    acc[2] = fmaf(bf16lo(v.y), w, acc[2]);
    acc[3] = fmaf(bf16hi(v.y), w, acc[3]);
    acc[4] = fmaf(bf16lo(v.z), w, acc[4]);
    acc[5] = fmaf(bf16hi(v.z), w, acc[5]);
    acc[6] = fmaf(bf16lo(v.w), w, acc[6]);
    acc[7] = fmaf(bf16hi(v.w), w, acc[7]);
  }
  // combine the 4 groups (after this, lanes with equal t are identical)
#pragma unroll
  for (int k = 0; k < 8; ++k) {
    acc[k] += __shfl_xor(acc[k], 16);
    acc[k] += __shfl_xor(acc[k], 32);
  }
  // self loop + conv bias
  {
    float wself = wd * wd;
    uint4 v = xwb4[(size_t)d * 16 + t];
    acc[0] = fmaf(bf16lo(v.x), wself, acc[0]);
    acc[1] = fmaf(bf16hi(v.x), wself, acc[1]);
    acc[2] = fmaf(bf16lo(v.y), wself, acc[2]);
    acc[3] = fmaf(bf16hi(v.y), wself, acc[3]);
    acc[4] = fmaf(bf16lo(v.z), wself, acc[4]);
    acc[5] = fmaf(bf16hi(v.z), wself, acc[5]);
    acc[6] = fmaf(bf16lo(v.w), wself, acc[6]);
    acc[7] = fmaf(bf16hi(v.w), wself, acc[7]);
    float4 c0 = *reinterpret_cast<const float4*>(cb + 8 * t);
    float4 c1 = *reinterpret_cast<const float4*>(cb + 8 * t + 4);
    acc[0] += c0.x; acc[1] += c0.y; acc[2] += c0.z; acc[3] += c0.w;
    acc[4] += c1.x; acc[5] += c1.y; acc[6] += c1.z; acc[7] += c1.w;
  }
  // LayerNorm over 128 channels (16 sublanes x 8)
  float s = acc[0] + acc[1] + acc[2] + acc[3] + acc[4] + acc[5] + acc[6] + acc[7];
#pragma unroll
  for (int m = 1; m < 16; m <<= 1) s += __shfl_xor(s, m);
  float mu = s * (1.0f / HID);
  float sq = 0.0f;
#pragma unroll
  for (int k = 0; k < 8; ++k) {
    acc[k] -= mu;
    sq = fmaf(acc[k], acc[k], sq);
  }
#pragma unroll
  for (int m = 1; m < 16; m <<= 1) sq += __shfl_xor(sq, m);
  float rs = rsqrtf(sq * (1.0f / HID) + LN_EPS);
  float4 g0 = *reinterpret_cast<const float4*>(g + 8 * t);
  float4 g1 = *reinterpret_cast<const float4*>(g + 8 * t + 4);
  float4 b0 = *reinterpret_cast<const float4*>(b + 8 * t);
  float4 b1 = *reinterpret_cast<const float4*>(b + 8 * t + 4);
  float o[8];
  o[0] = acc[0] * rs * g0.x + b0.x;
  o[1] = acc[1] * rs * g0.y + b0.y;
  o[2] = acc[2] * rs * g0.z + b0.z;
  o[3] = acc[3] * rs * g0.w + b0.w;
  o[4] = acc[4] * rs * g1.x + b1.x;
  o[5] = acc[5] * rs * g1.y + b1.y;
  o[6] = acc[6] * rs * g1.z + b1.z;
  o[7] = acc[7] * rs * g1.w + b1.w;
#pragma unroll
  for (int k = 0; k < 8; ++k) o[k] = o[k] >= 0.0f ? o[k] : SLOPE * o[k];

  if (!PROJ) {
    if (grp == 0) {
      float4* op = reinterpret_cast<float4*>(outx + (size_t)d * HID + 8 * t);
      op[0] = make_float4(o[0], o[1], o[2], o[3]);
      op[1] = make_float4(o[4], o[5], o[6], o[7]);
    }
  } else {
    float4 eu0 = *reinterpret_cast<const float4*>(eW + 8 * t);
    float4 eu1 = *reinterpret_cast<const float4*>(eW + 8 * t + 4);
    float4 ef0 = *reinterpret_cast<const float4*>(eW + HID + 8 * t);
    float4 ef1 = *reinterpret_cast<const float4*>(eW + HID + 8 * t + 4);
    float4 ru0 = *reinterpret_cast<const float4*>(rW + 8 * t);
    float4 ru1 = *reinterpret_cast<const float4*>(rW + 8 * t + 4);
    float4 rf0 = *reinterpret_cast<const float4*>(rW + HID + 8 * t);
    float4 rf1 = *reinterpret_cast<const float4*>(rW + HID + 8 * t + 4);
    float pa = o[0]*eu0.x + o[1]*eu0.y + o[2]*eu0.z + o[3]*eu0.w
             + o[4]*eu1.x + o[5]*eu1.y + o[6]*eu1.z + o[7]*eu1.w;
    float pb = o[0]*ef0.x + o[1]*ef0.y + o[2]*ef0.z + o[3]*ef0.w
             + o[4]*ef1.x + o[5]*ef1.y + o[6]*ef1.z + o[7]*ef1.w;
    float pc = o[0]*ru0.x + o[1]*ru0.y + o[2]*ru0.z + o[3]*ru0.w
             + o[4]*ru1.x + o[5]*ru1.y + o[6]*ru1.z + o[7]*ru1.w;
    float pd = o[0]*rf0.x + o[1]*rf0.y + o[2]*rf0.z + o[3]*rf0.w
             + o[4]*rf1.x + o[5]*rf1.y + o[6]*rf1.z + o[7]*rf1.w;
#pragma unroll
    for (int m = 1; m < 16; m <<= 1) {
      pa += __shfl_xor(pa, m);
      pb += __shfl_xor(pb, m);
      pc += __shfl_xor(pc, m);
      pd += __shfl_xor(pd, m);
    }
    if (lane == 0) table[d] = make_float4(pa, pb, pc, pd);
  }
}

// one thread per prediction pair
__global__ void pair_kernel(const int* __restrict__ eu, const int* __restrict__ ef,
                            const float4* __restrict__ table,
                            const float* __restrict__ eb, const float* __restrict__ rb,
                            float* __restrict__ out_exist, float* __restrict__ out_rating,
                            int Ep) {
  int i = blockIdx.x * blockDim.x + threadIdx.x;
  if (i >= Ep) return;
  float4 tu = table[eu[i]];
  float4 tf = table[ef[i]];
  float pe = tu.x + tf.y + eb[0];
  float pr = tu.z + tf.w + rb[0];
  out_exist[i]  = 1.0f / (1.0f + expf(-pe));
  out_rating[i] = 1.0f + 4.0f / (1.0f + expf(-pr));
}

extern "C" void kernel_launch(void* const* d_in, const int* in_sizes, int n_in,
                              void* d_out, int out_size, void* d_ws, size_t ws_size,
                              hipStream_t stream) {
  const float* u_feat = (const float*)d_in[0];
  const float* f_feat = (const float*)d_in[1];
  const int*   ei     = (const int*)d_in[2];
  const int*   eu     = (const int*)d_in[3];
  const int*   ef     = (const int*)d_in[4];
  const float* u_W  = (const float*)d_in[5];
  const float* u_b  = (const float*)d_in[6];
  const float* f_W  = (const float*)d_in[7];
  const float* f_b  = (const float*)d_in[8];
  const float* c1_W = (const float*)d_in[9];
  const float* c1_b = (const float*)d_in[10];
  const float* c2_W = (const float*)d_in[11];
  const float* c2_b = (const float*)d_in[12];
  const float* n1_g = (const float*)d_in[13];
  const float* n1_b = (const float*)d_in[14];
  const float* n2_g = (const float*)d_in[15];
  const float* n2_b = (const float*)d_in[16];
  const float* e_W  = (const float*)d_in[17];
  const float* e_b  = (const float*)d_in[18];
  const float* r_W  = (const float*)d_in[19];
  const float* r_b  = (const float*)d_in[20];

  int n_u = in_sizes[0] / 64;
  int n_f = in_sizes[1] / HID;
  int n   = n_u + n_f;
  int E   = in_sizes[2] / 2;
  int Ep  = in_sizes[3];
  int nbuck = (n + (1 << BSHIFT) - 1) >> BSHIFT;
  int nkey  = nbuck << SUBLOG;

  const int* src = ei;
  const int* dst = ei + E;

  float*        x      = (float*)d_ws;                            // n*HID f32
  unsigned int* xwb    = (unsigned int*)(x + (size_t)n * HID);    // n*HID/2 uint
  float4*       table  = (float4*)(xwb + (size_t)n * (HID / 2));  // n float4
  unsigned int* ebuf   = (unsigned int*)(table + n);              // E uint (packed)
  uint2*        ecol   = (uint2*)(ebuf + E);                      // E uint2 (src, w)
  float*        dinv   = (float*)(ecol + E);                      // n f32
  int*          rowptr = (int*)(dinv + n);                        // n+1 int
  int*          cnt2   = rowptr + n + 1;                          // nkey int
  int*          rowptr2= cnt2 + nkey;                             // nkey+1 int
  int*          blocksum = rowptr2 + nkey + 1;                    // NB_SCAN int
  int*          bcur   = blocksum + NB_SCAN;                      // nkey int

  // ---- bucketed edge sort (by dst>>6, XCD-aligned sub-segments) ----
  zero_int_kernel<<<(nkey + 255) / 256, 256, 0, stream>>>(cnt2, nkey);
  hist2_kernel<<<(E + 255) / 256, 256, 0, stream>>>(dst, cnt2, E);
  scan_pass1<<<NB_SCAN, NT_SCAN, 0, stream>>>(cnt2, blocksum, nkey);
  scan_pass2<<<1, NB_SCAN, 0, stream>>>(blocksum);
  scan_pass3<<<NB_SCAN, NT_SCAN, 0, stream>>>(cnt2, blocksum, rowptr2, bcur, nkey);
  bucket_scatter_kernel<<<(E + 255) / 256, 256, 0, stream>>>(src, dst, bcur, ebuf, E);

  // ---- per-node rowptr/dinv from bucketed edges, then per-bucket CSR fill ----
  deg_rowptr_kernel<<<nbuck, 256, 0, stream>>>(ebuf, rowptr2, rowptr, dinv, n, nbuck, E);
  fill_bucket_kernel<<<nbuck, 256, 0, stream>>>(ebuf, rowptr2, rowptr, dinv, ecol, n);

  // ---- input embeddings (f32 x) ----
  dense_mr_kernel<64, 32, false><<<(n_u + 31) / 32, 256, 0, stream>>>(
      u_feat, u_W, u_b, x, nullptr, n_u);
  dense_mr_kernel<128, 32, false><<<(n_f + 31) / 32, 256, 0, stream>>>(
      f_feat, f_W, f_b, x + (size_t)n_u * HID, nullptr, n_f);

  // ---- layer 1 ----
  dense_mr_kernel<128, 32, true><<<(n + 31) / 32, 256, 0, stream>>>(
      x, c1_W, nullptr, nullptr, xwb, n);
  gather_norm_kernel<false><<<(n + 3) / 4, 256, 0, stream>>>(
      rowptr, ecol, (const uint4*)xwb, dinv, c1_b, n1_g, n1_b,
      nullptr, nullptr, x, nullptr, n);

  // ---- layer 2 (fused prediction-head projection) ----
  dense_mr_kernel<128, 32, true><<<(n + 31) / 32, 256, 0, stream>>>(
      x, c2_W, nullptr, nullptr, xwb, n);
  gather_norm_kernel<true><<<(n + 3) / 4, 256, 0, stream>>>(
      rowptr, ecol, (const uint4*)xwb, dinv, c2_b, n2_g, n2_b,
      e_W, r_W, nullptr, table, n);

  // ---- per-pair combine ----
  float* out_exist  = (float*)d_out;
  float* out_rating = out_exist + Ep;
  pair_kernel<<<(Ep + 255) / 256, 256, 0, stream>>>(eu, ef, table, e_b, r_b,
                                                    out_exist, out_rating, Ep);
}